// Round 8
// baseline (274.082 us; speedup 1.0000x reference)
//
#include <hip/hip_runtime.h>

// spike_seq: (T=1024, B=16384, 2) fp32; w_exc={0.7,1.0}; w_inh=-1.0.
// Outputs flat: spk_rec (T*B) then mem_rec (T*B), fp32.
#define T_LEN 1024
#define B_N   16384
#define NB    256             // neurons per block  (the round-8 change)
#define PH    8               // timesteps per phase
#define NPH   (T_LEN / PH)    // 128
#define RIN   3               // IN ring depth (48 KiB)

// R0-R7 post-mortems: reg-pipeline depth (R2/R5), wave-specialized vmcnt
// domains (R4/R6), and store-instruction packing (R7) all landed at 80-105us
// / 2.0-2.5 TB/s. The surviving discriminator vs fillBuffer (6.6 TB/s) and
// the m13 copy (6.3 TB/s) is CONTIGUITY: they touch >=1KB per burst; our
// 64-neuron blocks touched 256B (out) / 512B (in) per row at 64KB stride,
// and a DRAM page (~1-2KB) spans 4-8 mutually-unsynchronized blocks =>
// chronic page-splitting at ~38% efficiency.
// Fix: 64 blocks x 256 neurons. Per row: input 2KB contiguous (loader wave,
// global_load_lds dwordx4 = 1KB/instr), output 1KB/plane from 4 compute
// waves that are barrier-synced per phase (stores to one page land within
// one ~300cy window). Compute stores directly to global: its vmcnt domain is
// STORE-ONLY (loader owns all loads), so load-waits can't chain behind store
// acks. Loader uses counted vmcnt(16) (never 0 mid-loop).
__shared__ __align__(16) float2 IN_lds[RIN][PH][NB];  // 48 KiB input ring

static __device__ __forceinline__ void block_barrier() {
  asm volatile("" ::: "memory");   // compiler fence: no mem-op motion
  __builtin_amdgcn_s_barrier();
  asm volatile("" ::: "memory");
}

__global__ __launch_bounds__(320, 1) void FMFMNeuronInhib_34033320854098_kernel(
    const float* __restrict__ x,      // (T, B, 2)
    const float* __restrict__ w_exc,  // {0.7, 1.0}
    const float* __restrict__ w_inh,  // {-1.0}
    float* __restrict__ out) {
#pragma clang fp contract(off)
  const int lane = threadIdx.x & 63;
  const int wid  = threadIdx.x >> 6;   // 0..3 compute, 4 loader
  const int nb0  = blockIdx.x * NB;    // this block's first neuron

  float* __restrict__ spk_out = out;
  float* __restrict__ mem_out = out + (size_t)T_LEN * B_N;

  if (wid == 4) {
    // ---------------- loader ----------------
    // Phase q: rows t=q*PH..q*PH+7; each row slice = NB float2 = 2KB = two
    // dwordx4 global_load_lds (1KB each: 64 lanes x 16B). LDS dest is
    // wave-uniform base + lane*16 (linear, matches [PH][NB]float2 rows);
    // global src is per-lane.
    auto issue_phase = [&](int q) {
      const int slot = q % RIN;
#pragma unroll
      for (int u = 0; u < PH; ++u) {
        const int t = q * PH + u;
#pragma unroll
        for (int h = 0; h < 2; ++h) {  // half-rows of 256 floats (1KB)
          const float* src =
              x + ((size_t)t * B_N + nb0) * 2 + h * 256 + lane * 4;
          __builtin_amdgcn_global_load_lds(
              (const __attribute__((address_space(1))) void*)src,
              (__attribute__((address_space(3))) void*)&IN_lds[slot][u][h * 128],
              16, 0, 0);
        }
      }
    };
    issue_phase(0);
    issue_phase(1);                                   // 32 instr in flight
    asm volatile("s_waitcnt vmcnt(16)" ::: "memory"); // phase 0 landed
    block_barrier();                                  // prologue barrier
    for (int p = 0; p < NPH; ++p) {
      if (p + 2 < NPH) {
        // Slot (p+2)%RIN == (p-1)%RIN was fully consumed in phase p-1
        // (compute's lgkmcnt(0) before the barrier that opened phase p).
        issue_phase(p + 2);                             // in flight: p+1,p+2
        asm volatile("s_waitcnt vmcnt(16)" ::: "memory"); // p+1 landed,
      } else {                                           // keep p+2 in flight
        asm volatile("s_waitcnt vmcnt(0)" ::: "memory"); // tail drain
      }
      block_barrier();
    }
  } else {
    // ---------------- compute (x4 waves): VALU + LDS reads + direct stores --
    const float w0 = w_exc[0];
    const float w1 = w_exc[1];
    const float wi = w_inh[0];
    const int nmy = wid * 64 + lane;   // neuron offset within the block
    float mem = 0.0f, inh = 0.0f;
    block_barrier();                                  // prologue barrier
    for (int p = 0; p < NPH; ++p) {
      const int slot = p % RIN;
      float2 xv[PH];
#pragma unroll
      for (int u = 0; u < PH; ++u) xv[u] = IN_lds[slot][u][nmy];  // 2-way
                                                                  // alias=free
#pragma unroll
      for (int u = 0; u < PH; ++u) {
        const int t = p * PH + u;
        const float x0 = xv[u].x;
        const float x1 = xv[u].y;
        // Exact reference op order; no FMA contraction (1 ulp flips a spike).
        const float cur_exc = x0 * w0 + x1 * w1;   // x @ w_exc^T
        inh = 0.6f * inh + x0;                     // inh decay + feed
        const float cur = cur_exc + wi * inh;      // wi = -1.0 exact
        // (mem-1>0) == (mem>1) exactly; reset*1.0f == reset.
        const float reset = (mem > 1.0f) ? 1.0f : 0.0f;
        mem = 0.9f * mem + cur - reset;
        const float spk = (mem > 1.0f) ? 1.0f : 0.0f;
        const size_t idx = (size_t)t * B_N + nb0 + nmy;
        // Direct stores, fire-and-forget: this wave's vmcnt domain contains
        // no loads, so nothing ever waits on these acks. The 4 compute waves
        // jointly cover 1KB contiguous per row per plane within one phase.
        spk_out[idx] = spk;
        mem_out[idx] = mem;
      }
      // All ds_reads retired -> IN slot reusable by the loader next phase.
      asm volatile("s_waitcnt lgkmcnt(0)" ::: "memory");
      block_barrier();
    }
  }
}

extern "C" void kernel_launch(void* const* d_in, const int* in_sizes, int n_in,
                              void* d_out, int out_size, void* d_ws, size_t ws_size,
                              hipStream_t stream) {
  const float* x     = (const float*)d_in[0];  // spike_seq, T*B*2 floats
  const float* w_exc = (const float*)d_in[1];  // 2 floats
  const float* w_inh = (const float*)d_in[2];  // 1 float
  float* out = (float*)d_out;                  // spk_rec ++ mem_rec

  dim3 grid(B_N / NB);   // 64 blocks, 256 neurons each
  dim3 block(320);       // w0-w3 compute, w4 loader
  hipLaunchKernelGGL(FMFMNeuronInhib_34033320854098_kernel, grid, block, 0, stream,
                     x, w_exc, w_inh, out);
}

// Round 9
// 266.529 us; speedup vs baseline: 1.0283x; 1.0283x over previous
//
#include <hip/hip_runtime.h>

// spike_seq: (T=1024, B=16384, 2) fp32, values EXACTLY 0.0/1.0.
// Outputs flat: spk_rec (T*B) then mem_rec (T*B), fp32.
#define T_LEN 1024
#define B_N   16384
#define PH    16                   // timesteps per phase
#define NPH   (T_LEN / PH)         // 64
#define RING  7                    // OUT ring depth == number of storer waves
#define CW_WORDS (B_N * (T_LEN / 16))   // 1,048,576 dwords = 4 MB compressed

// ---------------------------------------------------------------------------
// K1: compress input to 2 bits/sample. Word (j, n) packs t=16j..16j+15 for
// neuron n: bit(2k)=x0!=0, bit(2k+1)=x1!=0. Layout cw[j*B_N + n] so BOTH
// K1 stores and K2 reads are lane-coalesced. 1M threads — pure-TLP regime.
__global__ __launch_bounds__(256) void k1_compress(
    const float* __restrict__ x, unsigned int* __restrict__ cw) {
  const int tid = blockIdx.x * 256 + threadIdx.x;  // 0..CW_WORDS-1
  const int n = tid & (B_N - 1);
  const int j = tid >> 14;                         // 0..63
  const float2* xp = (const float2*)x;
  unsigned int w = 0;
#pragma unroll
  for (int k = 0; k < 16; ++k) {
    const float2 v = xp[(size_t)(16 * j + k) * B_N + n];  // 512B/wave, coalesced
    w |= (v.x != 0.0f ? 1u : 0u) << (2 * k);
    w |= (v.y != 0.0f ? 1u : 0u) << (2 * k + 1);
  }
  cw[(size_t)j * B_N + n] = w;
}

// ---------------------------------------------------------------------------
// K2: scan with ZERO global loads in the loop (block's whole input = 16 KB
// of bits, LDS-resident). 8 waves: w0 compute, w1..w7 storers. Output ring
// RING x 8 KB; storer s owns slot s and phases p == s (mod 7) — all stores
// fire-and-forget dwordx4 (R7 transpose planes), 7 independent store streams
// per CU. R6's proven flag protocol; no barrier after startup.
__shared__ float SPK[RING][PH][64];       // 28 KiB
__shared__ float MEM[RING][PH][64];       // 28 KiB
__shared__ unsigned int INB[64][65];      // 16.25 KiB (+1 pad: bank spread)
__shared__ int F[8];  // F[0]=prod (compute), F[1+s]=done (storer s)

#define WGSC __HIP_MEMORY_SCOPE_WORKGROUP
static __device__ __forceinline__ int ld_flag(int i) {
  return __hip_atomic_load(&F[i], __ATOMIC_ACQUIRE, WGSC);
}
static __device__ __forceinline__ void st_flag(int i, int v) {
  __hip_atomic_store(&F[i], v, __ATOMIC_RELEASE, WGSC);
}

__global__ __launch_bounds__(512, 1) void FMFMNeuronInhib_34033320854098_kernel(
    const unsigned int* __restrict__ cw,  // compressed input (from K1)
    const float* __restrict__ w_exc,      // {0.7, 1.0}
    const float* __restrict__ w_inh,      // {-1.0}
    float* __restrict__ out) {
#pragma clang fp contract(off)
  const int lane = threadIdx.x & 63;
  const int wid  = threadIdx.x >> 6;   // 0=compute, 1..7=storers
  const int nb0  = blockIdx.x * 64;

  float* __restrict__ spk_out = out;
  float* __restrict__ mem_out = out + (size_t)T_LEN * B_N;

  if (threadIdx.x < 8) F[threadIdx.x] = 0;
  // Cooperative INB load: 4096 words / 512 threads = 8 each, coalesced.
#pragma unroll
  for (int i = 0; i < 8; ++i) {
    const int idx = threadIdx.x + 512 * i;   // 0..4095
    const int L = idx & 63, j = idx >> 6;
    INB[L][j] = cw[(size_t)j * B_N + nb0 + L];
  }
  __syncthreads();  // the only block-wide barrier

  if (wid == 0) {
    // ---------------- compute: VALU + LDS only ----------------
    const float w0 = w_exc[0];
    const float w1 = w_exc[1];
    const float wi = w_inh[0];
    float mem = 0.0f, inh = 0.0f;
    for (int p = 0; p < NPH; ++p) {
      const int s = p % RING;
      // Slot s was last used at phase p-RING by storer s.
      if (p >= RING)
        while (ld_flag(1 + s) < p - (RING - 1)) __builtin_amdgcn_s_sleep(1);
      const unsigned int w = INB[lane][p];  // 16 steps x 2 bits, bank-spread
#pragma unroll
      for (int u = 0; u < PH; ++u) {
        const float x0 = (float)((w >> (2 * u)) & 1u);      // exact 0.0/1.0
        const float x1 = (float)((w >> (2 * u + 1)) & 1u);  // == original x
        // Exact reference op order; no FMA contraction (1 ulp flips a spike).
        const float cur_exc = x0 * w0 + x1 * w1;   // x @ w_exc^T
        inh = 0.6f * inh + x0;                     // inh decay + feed
        const float cur = cur_exc + wi * inh;      // wi = -1.0 exact
        // (mem-1>0) == (mem>1) exactly; reset*1.0f == reset.
        const float reset = (mem > 1.0f) ? 1.0f : 0.0f;
        mem = 0.9f * mem + cur - reset;
        const float spk = (mem > 1.0f) ? 1.0f : 0.0f;
        SPK[s][u][lane] = spk;
        MEM[s][u][lane] = mem;
      }
      asm volatile("s_waitcnt lgkmcnt(0)" ::: "memory");  // writes visible
      if (lane == 0) st_flag(0, p + 1);
    }
  } else {
    // ---------------- storer s0: phases p == s0 (mod 7), slot s0 ----------
    const int s0 = wid - 1;              // 0..6
    const int r  = lane >> 4;            // row-within-group
    const int n0 = (lane & 15) * 4;      // 4 adjacent neurons
    for (int p = s0; p < NPH; p += RING) {
      while (ld_flag(0) < p + 1) __builtin_amdgcn_s_sleep(1);
      const int tb = p * PH;
#pragma unroll
      for (int j = 0; j < 4; ++j) {      // 4+4 dwordx4 instrs cover 16 rows
        const int row = 4 * j + r;
        const float4 vs = *(const float4*)&SPK[s0][row][n0];
        *(float4*)&spk_out[(size_t)(tb + row) * B_N + nb0 + n0] = vs;
        const float4 vm = *(const float4*)&MEM[s0][row][n0];
        *(float4*)&mem_out[(size_t)(tb + row) * B_N + nb0 + n0] = vm;
      }
      // ds_reads retired (data already in store regs) -> slot reusable.
      // Global stores drain in this wave's own vmcnt domain; nothing waits.
      asm volatile("s_waitcnt lgkmcnt(0)" ::: "memory");
      if (lane == 0) st_flag(1 + s0, p + 1);
    }
  }
}

extern "C" void kernel_launch(void* const* d_in, const int* in_sizes, int n_in,
                              void* d_out, int out_size, void* d_ws, size_t ws_size,
                              hipStream_t stream) {
  const float* x     = (const float*)d_in[0];
  const float* w_exc = (const float*)d_in[1];
  const float* w_inh = (const float*)d_in[2];
  float* out = (float*)d_out;
  unsigned int* cw = (unsigned int*)d_ws;   // 4 MB compressed input

  // Pass 1: compress (pure-TLP read regime).
  hipLaunchKernelGGL(k1_compress, dim3(CW_WORDS / 256), dim3(256), 0, stream,
                     x, cw);
  // Pass 2: scan (store-only regime), stream-ordered after K1.
  hipLaunchKernelGGL(FMFMNeuronInhib_34033320854098_kernel, dim3(B_N / 64),
                     dim3(512), 0, stream, cw, w_exc, w_inh, out);
}